// Round 22
// baseline (604.733 us; speedup 1.0000x reference)
//
#include <hip/hip_runtime.h>
#include <math.h>

#define B_N 2048
#define D_N 1024
#define H_N 32768
#define K_SEL 256
#define M_CAND 320
#define CAP_C 384
#define BAND_CAP 160
#define DELTA 0.03f
#define EPS_V 1e-5f

typedef __bf16 bf16x8 __attribute__((ext_vector_type(8)));
typedef float f32x4 __attribute__((ext_vector_type(4)));

__device__ __forceinline__ unsigned short f2bf(float f) {
    unsigned u = __float_as_uint(f);
    unsigned r = u + 0x7FFFu + ((u >> 16) & 1u);   // RNE
    return (unsigned short)(r >> 16);
}

__device__ __forceinline__ float bf2f(unsigned short b) {
    return __uint_as_float((unsigned)b << 16);
}

// async global->LDS, 16B per lane; LDS dest is wave-uniform base + lane*16
__device__ __forceinline__ void gload16(const void* g, void* l) {
    __builtin_amdgcn_global_load_lds(
        (const __attribute__((address_space(1))) void*)g,
        (__attribute__((address_space(3))) void*)l, 16, 0, 0);
}

// ---------------- LN preprocess (f64 stats) -> bf16 xn + f32/f64 mu,std ----------------
__global__ __launch_bounds__(256) void ln_kernel(const float* __restrict__ x,
        unsigned short* __restrict__ xnbf, float* __restrict__ mu_out, float* __restrict__ std_out,
        double* __restrict__ mud, double* __restrict__ sivd) {
    int b = blockIdx.x, t = threadIdx.x;
    const float4* row = (const float4*)(x + (size_t)b * D_N);
    float4 v = row[t];
    double s  = (double)v.x + (double)v.y + (double)v.z + (double)v.w;
    double ss = (double)v.x*v.x + (double)v.y*v.y + (double)v.z*v.z + (double)v.w*v.w;
    #pragma unroll
    for (int off = 32; off > 0; off >>= 1) {
        s  += __shfl_down(s, off);
        ss += __shfl_down(ss, off);
    }
    __shared__ double ls[4], lss[4];
    __shared__ double smu, sinv;
    int w = t >> 6;
    if ((t & 63) == 0) { ls[w] = s; lss[w] = ss; }
    __syncthreads();
    if (t == 0) {
        double S  = ls[0] + ls[1] + ls[2] + ls[3];
        double SS = lss[0] + lss[1] + lss[2] + lss[3];
        double mu = S / (double)D_N;
        double var = (SS - S * S / (double)D_N) / (double)(D_N - 1);
        double sd = sqrt(var > 0.0 ? var : 0.0);
        smu = mu; sinv = 1.0 / (sd + 1e-5);
        mu_out[b] = (float)mu; std_out[b] = (float)sd;
        mud[b] = mu; sivd[b] = sinv;
    }
    __syncthreads();
    double mu = smu, inv = sinv;
    ushort4 o;
    o.x = f2bf((float)(((double)v.x - mu) * inv)); o.y = f2bf((float)(((double)v.y - mu) * inv));
    o.z = f2bf((float)(((double)v.z - mu) * inv)); o.w = f2bf((float)(((double)v.w - mu) * inv));
    *(ushort4*)(xnbf + (size_t)b * D_N + t * 4) = o;
}

// ---------------- W_enc: f64 row norm, bf16 normalized rows ----------------
__global__ __launch_bounds__(256) void wconv_kernel(const float* __restrict__ W,
        unsigned short* __restrict__ Wbf, double* __restrict__ inv_norm_d) {
    int h = blockIdx.x, t = threadIdx.x;
    const float4* row = (const float4*)(W + (size_t)h * D_N);
    float4 v = row[t];
    double ss = (double)v.x*v.x + (double)v.y*v.y + (double)v.z*v.z + (double)v.w*v.w;
    #pragma unroll
    for (int off = 32; off > 0; off >>= 1) ss += __shfl_down(ss, off);
    __shared__ double lss[4];
    __shared__ float sinv;
    int w = t >> 6;
    if ((t & 63) == 0) lss[w] = ss;
    __syncthreads();
    if (t == 0) {
        double SS = lss[0] + lss[1] + lss[2] + lss[3];
        double n = sqrt(SS);
        if (n < 1e-12) n = 1e-12;
        inv_norm_d[h] = 1.0 / n;
        sinv = (float)(1.0 / n);
    }
    __syncthreads();
    float invf = sinv;
    ushort4 o;
    o.x = f2bf(v.x * invf); o.y = f2bf(v.y * invf);
    o.z = f2bf(v.z * invf); o.w = f2bf(v.w * invf);
    *(ushort4*)(Wbf + (size_t)h * D_N + t * 4) = o;
}

// ---------------- bf16 MFMA GEMM: 256x256 tile, BK=64, 512 threads (8 waves 2x4),
//   r13 schedule scaled: double-buffered global_load_lds, counted vmcnt(8), raw
//   barriers, pre-swizzled source (j' = j ^ (row&7)), bm-fastest grid. LDS 128 KB. ----
__global__ __launch_bounds__(512) void enc_gemm_bf16(const unsigned short* __restrict__ A,
        const unsigned short* __restrict__ Bm, float* __restrict__ C) {
    __shared__ alignas(16) unsigned short SM[2 * 2 * 16384];   // 128 KB: buf{0,1} x (A|B)
    int t = threadIdx.x;                 // 0..511
    int w = t >> 6, lane = t & 63;       // 8 waves
    int bm = blockIdx.x, bn = blockIdx.y;  // bm fastest (B-panel locality)
    int wr = w >> 2, wc = w & 3;         // 2 x 4 wave grid; per-wave out 128x64
    int fr = lane & 15, kq = lane >> 4;

    size_t arow0 = (size_t)bm * 256;
    size_t brow0 = (size_t)bn * 256;

    // staging map: call q, wave w, lane l -> LDS chunk (row = q*64 + w*8 + (l>>3), j' = l&7)
    // holds global chunk j = j' ^ (row&7) = (l&7) ^ (l>>3)   [row&7 == l>>3]
    int rsub = lane >> 3;
    int jl   = (lane & 7) ^ rsub;
    const unsigned short* gAq[4];
    const unsigned short* gBq[4];
    #pragma unroll
    for (int q = 0; q < 4; q++) {
        int row = q * 64 + w * 8 + rsub;
        gAq[q] = A  + (arow0 + row) * D_N + jl * 8;
        gBq[q] = Bm + (brow0 + row) * D_N + jl * 8;
    }

    f32x4 acc[8][4];
    #pragma unroll
    for (int i = 0; i < 8; i++)
        #pragma unroll
        for (int j = 0; j < 4; j++)
            acc[i][j] = (f32x4){0.f, 0.f, 0.f, 0.f};

    // STAGE(buf, k0): 8 gload16 per thread (4 A + 4 B), linear LDS dest.
    auto STAGE = [&](int buf, int k0) {
        char* Ab = (char*)(SM + buf * 32768);   // 64 KB per buffer
        char* Bb = Ab + 32768;                  // bytes: B region after 16384 shorts of A
        #pragma unroll
        for (int q = 0; q < 4; q++)
            gload16(gAq[q] + k0, Ab + (q * 8 + w) * 1024);
        #pragma unroll
        for (int q = 0; q < 4; q++)
            gload16(gBq[q] + k0, Bb + (q * 8 + w) * 1024);
    };

    STAGE(0, 0);

    for (int ks = 0; ks < D_N / 64; ks++) {
        int cur = ks & 1;
        if (ks + 1 < D_N / 64) {
            STAGE(cur ^ 1, (ks + 1) * 64);
            asm volatile("s_waitcnt vmcnt(8)" ::: "memory");   // cur tile's 8 loads done
        } else {
            asm volatile("s_waitcnt vmcnt(0)" ::: "memory");
        }
        __builtin_amdgcn_s_barrier();
        __builtin_amdgcn_sched_barrier(0);

        const unsigned short* Ab = SM + cur * 32768;
        const unsigned short* Bb = Ab + 16384;
        #pragma unroll
        for (int kk = 0; kk < 2; kk++) {
            bf16x8 af[8], bfr[4];
            #pragma unroll
            for (int i = 0; i < 8; i++) {
                int ra = wr * 128 + i * 16 + fr;
                int ja = (kk * 4 + kq) ^ (ra & 7);
                af[i] = *(const bf16x8*)&Ab[ra * 64 + ja * 8];
            }
            #pragma unroll
            for (int j = 0; j < 4; j++) {
                int rb = wc * 64 + j * 16 + fr;
                int jb = (kk * 4 + kq) ^ (rb & 7);
                bfr[j] = *(const bf16x8*)&Bb[rb * 64 + jb * 8];
            }
            #pragma unroll
            for (int i = 0; i < 8; i++)
                #pragma unroll
                for (int j = 0; j < 4; j++)
                    acc[i][j] = __builtin_amdgcn_mfma_f32_16x16x32_bf16(af[i], bfr[j], acc[i][j], 0, 0, 0);
        }

        asm volatile("s_waitcnt lgkmcnt(0)" ::: "memory");   // my ds_reads of cur done
        __builtin_amdgcn_sched_barrier(0);
        __builtin_amdgcn_s_barrier();                        // all waves done -> buffer reusable
        __builtin_amdgcn_sched_barrier(0);
    }

    #pragma unroll
    for (int i = 0; i < 8; i++) {
        int r0 = bm * 256 + wr * 128 + i * 16 + kq * 4;
        #pragma unroll
        for (int j = 0; j < 4; j++) {
            int c = bn * 256 + wc * 64 + j * 16 + fr;
            #pragma unroll
            for (int r = 0; r < 4; r++)
                __builtin_nontemporal_store(acc[i][j][r], &C[(size_t)(r0 + r) * H_N + c]);
        }
    }
}

// ---------------- W_dec transpose [D][H] -> bf16 [H][D], ushort2 writes ----------------
__global__ void transpose_kernel(const float* __restrict__ in, unsigned short* __restrict__ out) {
    __shared__ float tile[64][33];   // [d][h]
    int tx = threadIdx.x, ty = threadIdx.y;
    int x  = blockIdx.x * 32 + tx;        // h
    int y0 = blockIdx.y * 64;             // d base
    #pragma unroll
    for (int j = ty; j < 64; j += 8)
        tile[j][tx] = in[(size_t)(y0 + j) * H_N + x];
    __syncthreads();
    int d2 = tx * 2;
    int hbase = blockIdx.x * 32;
    #pragma unroll
    for (int j = ty; j < 32; j += 8) {
        ushort2 o;
        o.x = f2bf(tile[d2][j]);
        o.y = f2bf(tile[d2 + 1][j]);
        *(ushort2*)(out + (size_t)(hbase + j) * D_N + y0 + d2) = o;
    }
}

// ---------------- candidate extraction: thresholded histogram, wave-parallel scan ----------
__global__ __launch_bounds__(1024) void candk_kernel(const float* __restrict__ lat,
        int* __restrict__ cand_idx, float* __restrict__ cand_val) {
    int b = blockIdx.x, t = threadIdx.x;
    const float4* row4 = (const float4*)(lat + (size_t)b * H_N);
    __shared__ unsigned hist[256];
    __shared__ int sh_tb, sh_pos;

    float4 fv[8];
    #pragma unroll
    for (int j = 0; j < 8; j++)
        fv[j] = row4[t + (j << 10)];

    if (t < 256) hist[t] = 0;
    if (t == 0) { sh_pos = 0; sh_tb = 0; }
    __syncthreads();
    #pragma unroll
    for (int j = 0; j < 8; j++) {
        const float4 v = fv[j];
        #pragma unroll
        for (int c = 0; c < 4; c++) {
            float f = (c == 0) ? v.x : (c == 1) ? v.y : (c == 2) ? v.z : v.w;
            if (f >= 1.75f) {
                int bin = (int)((f - 1.75f) * 128.0f);
                bin = bin > 255 ? 255 : bin;
                atomicAdd(&hist[bin], 1u);
            }
        }
    }
    __syncthreads();
    if (t < 64) {
        unsigned h0 = hist[4 * t], h1 = hist[4 * t + 1];
        unsigned h2 = hist[4 * t + 2], h3 = hist[4 * t + 3];
        unsigned s = h0 + h1 + h2 + h3;
        #pragma unroll
        for (int off = 1; off < 64; off <<= 1) {
            unsigned v = __shfl_down(s, off);
            if (t + off < 64) s += v;
        }
        unsigned S0 = s, S1 = s - h0, S2 = S1 - h1, S3 = S2 - h2;
        int mj = -1;
        if (S0 >= (unsigned)M_CAND) mj = 4 * t;
        if (S1 >= (unsigned)M_CAND) mj = 4 * t + 1;
        if (S2 >= (unsigned)M_CAND) mj = 4 * t + 2;
        if (S3 >= (unsigned)M_CAND) mj = 4 * t + 3;
        #pragma unroll
        for (int off = 32; off > 0; off >>= 1) {
            int v = __shfl_down(mj, off);
            if (t + off < 64 && v > mj) mj = v;
        }
        if (t == 0) sh_tb = mj > 0 ? mj : 0;
    }
    __syncthreads();
    int tb = sh_tb;
    #pragma unroll
    for (int j = 0; j < 8; j++) {
        const float4 v = fv[j];
        #pragma unroll
        for (int c = 0; c < 4; c++) {
            float f = (c == 0) ? v.x : (c == 1) ? v.y : (c == 2) ? v.z : v.w;
            if (f >= 1.75f) {
                int bin = (int)((f - 1.75f) * 128.0f);
                bin = bin > 255 ? 255 : bin;
                if (bin >= tb) {
                    int p = atomicAdd(&sh_pos, 1);
                    if (p < CAP_C) {
                        cand_idx[(size_t)b * CAP_C + p] = 4 * (t + (j << 10)) + c;
                        cand_val[(size_t)b * CAP_C + p] = f;
                    }
                }
            }
        }
    }
    __syncthreads();
    int pos = sh_pos < CAP_C ? sh_pos : CAP_C;
    for (int p = pos + t; p < CAP_C; p += 1024) {
        cand_idx[(size_t)b * CAP_C + p] = -(p + 1);
        cand_val[(size_t)b * CAP_C + p] = -1e30f;
    }
}

// ---------------- fused band-classify + f64 boundary refine + select ----------------
__global__ __launch_bounds__(512) void resolve_kernel(const float* __restrict__ x,
        const float* __restrict__ Wenc, const double* __restrict__ invn_d,
        const int* __restrict__ candidx, const float* __restrict__ candval,
        int* __restrict__ sel_idx, float* __restrict__ sel_val) {
    int b = blockIdx.x, t = threadIdx.x;
    int lane = t & 63, w = t >> 6;
    __shared__ float cv[CAP_C];
    __shared__ int   ci[CAP_C];
    __shared__ float sh_v256;
    __shared__ int sh_nIn, sh_bcnt;
    __shared__ int bmem[BAND_CAP];
    __shared__ double bval[BAND_CAP];
    __shared__ double xs[D_N];
    __shared__ double red[8];
    __shared__ double smu, sinv;

    if (t == 0) { sh_nIn = 0; sh_bcnt = 0; }
    if (t < CAP_C) {
        cv[t] = candval[(size_t)b * CAP_C + t];
        ci[t] = candidx[(size_t)b * CAP_C + t];
    }
    float4 v;
    if (t < 256) {
        v = ((const float4*)(x + (size_t)b * D_N))[t];
        double s  = (double)v.x + (double)v.y + (double)v.z + (double)v.w;
        double ss = (double)v.x*v.x + (double)v.y*v.y + (double)v.z*v.z + (double)v.w*v.w;
        #pragma unroll
        for (int off = 32; off > 0; off >>= 1) {
            s  += __shfl_down(s, off);
            ss += __shfl_down(ss, off);
        }
        if (lane == 0) { red[w] = s; red[4 + w] = ss; }
    }
    __syncthreads();
    if (t == 0) {
        double S  = red[0] + red[1] + red[2] + red[3];
        double SS = red[4] + red[5] + red[6] + red[7];
        double mu = S / (double)D_N;
        double var = (SS - S * S / (double)D_N) / (double)(D_N - 1);
        double sd = sqrt(var > 0.0 ? var : 0.0);
        smu = mu; sinv = 1.0 / (sd + 1e-5);
    }
    __syncthreads();
    if (t < 256) {
        double mu = smu, inv = sinv;
        xs[4*t + 0] = ((double)v.x - mu) * inv;
        xs[4*t + 1] = ((double)v.y - mu) * inv;
        xs[4*t + 2] = ((double)v.z - mu) * inv;
        xs[4*t + 3] = ((double)v.w - mu) * inv;
    }
    int myr = 0;
    if (t < CAP_C) {
        float vv = cv[t]; int id = ci[t];
        for (int j = 0; j < CAP_C; j++) {
            float vj = cv[j];
            myr += (vj > vv) || (vj == vv && ci[j] < id);
        }
        if (myr == 255) sh_v256 = cv[t];
    }
    __syncthreads();
    float v256 = sh_v256;
    if (t < CAP_C) {
        float vv = cv[t];
        if (vv > v256 + DELTA) {
            sel_idx[(size_t)b * K_SEL + myr] = ci[t];
            sel_val[(size_t)b * K_SEL + myr] = vv;
            atomicAdd(&sh_nIn, 1);
        } else if (vv >= v256 - DELTA) {
            int p = atomicAdd(&sh_bcnt, 1);
            if (p < BAND_CAP) bmem[p] = t;
        }
    }
    __syncthreads();

    double xr[16];
    #pragma unroll
    for (int r = 0; r < 4; r++)
        #pragma unroll
        for (int j = 0; j < 4; j++)
            xr[r * 4 + j] = xs[256 * r + 4 * lane + j];

    int bcnt = sh_bcnt < BAND_CAP ? sh_bcnt : BAND_CAP;
    const float4* W4 = (const float4*)Wenc;
    for (int m = w; m < bcnt; m += 8) {
        int c = bmem[m];
        int h = ci[c];
        const float4* wr = W4 + (size_t)h * 256 + lane;
        float4 w0 = wr[0], w1 = wr[64], w2 = wr[128], w3 = wr[192];
        double a0 = (double)w0.x*xr[0]  + (double)w0.y*xr[1]  + (double)w0.z*xr[2]  + (double)w0.w*xr[3];
        double a1 = (double)w1.x*xr[4]  + (double)w1.y*xr[5]  + (double)w1.z*xr[6]  + (double)w1.w*xr[7];
        double a2 = (double)w2.x*xr[8]  + (double)w2.y*xr[9]  + (double)w2.z*xr[10] + (double)w2.w*xr[11];
        double a3 = (double)w3.x*xr[12] + (double)w3.y*xr[13] + (double)w3.z*xr[14] + (double)w3.w*xr[15];
        double p = (a0 + a1) + (a2 + a3);
        #pragma unroll
        for (int off = 32; off > 0; off >>= 1) p += __shfl_down(p, off);
        if (lane == 0) bval[m] = p * invn_d[h];
    }
    __syncthreads();

    int nIn = sh_nIn;
    int take = K_SEL - nIn;
    if (t < bcnt) {
        double vv = bval[t]; int id = ci[bmem[t]];
        int rb = 0;
        for (int j = 0; j < bcnt; j++) {
            double vj = bval[j];
            rb += (vj > vv) || (vj == vv && ci[bmem[j]] < id);
        }
        if (rb < take) {
            sel_idx[(size_t)b * K_SEL + nIn + rb] = id;
            sel_val[(size_t)b * K_SEL + nIn + rb] = (float)vv;
        }
    }
}

// ---------------- sparse decode (bf16 Wdt) + denorm ----------------
// 128 threads/block; each thread owns 8 contiguous d -> one uint4 (16B) per gathered
// row. Pure data-parallel over d. h clamped at staging. 4-deep prefetch.
__global__ __launch_bounds__(128) void decode_kernel(const int* __restrict__ sel_idx,
        const float* __restrict__ sel_val, const unsigned short* __restrict__ Wdt,
        const float* __restrict__ mu, const float* __restrict__ stdv,
        float* __restrict__ out) {
    int b = blockIdx.x, t = threadIdx.x;   // t in [0,128)
    __shared__ int sidx[K_SEL];
    __shared__ float sval[K_SEL];
    #pragma unroll
    for (int i = 0; i < 2; i++) {
        int k = t + i * 128;
        int h = sel_idx[(size_t)b * K_SEL + k];
        sidx[k] = ((unsigned)h < (unsigned)H_N) ? h : 0;
        sval[k] = sel_val[(size_t)b * K_SEL + k];
    }
    __syncthreads();
    const unsigned short* Wd = Wdt + t * 8;
    float acc[8] = {0.f, 0.f, 0.f, 0.f, 0.f, 0.f, 0.f, 0.f};
    uint4 wb[4];
    #pragma unroll
    for (int q = 0; q < 4; q++)
        wb[q] = *(const uint4*)(Wd + (size_t)sidx[q] * D_N);
    for (int k = 0; k < K_SEL; k += 4) {
        uint4 c0 = wb[0], c1 = wb[1], c2 = wb[2], c3 = wb[3];
        if (k + 4 < K_SEL) {
            #pragma unroll
            for (int q = 0; q < 4; q++)
                wb[q] = *(const uint4*)(Wd + (size_t)sidx[k + 4 + q] * D_N);
        }
        float v0 = sval[k], v1 = sval[k + 1], v2 = sval[k + 2], v3 = sval[k + 3];
        acc[0] += v0 * __uint_as_float(c0.x << 16);
        acc[1] += v0 * __uint_as_float(c0.x & 0xFFFF0000u);
        acc[2] += v0 * __uint_as_float(c0.y << 16);
        acc[3] += v0 * __uint_as_float(c0.y & 0xFFFF0000u);
        acc[4] += v0 * __uint_as_float(c0.z << 16);
        acc[5] += v0 * __uint_as_float(c0.z & 0xFFFF0000u);
        acc[6] += v0 * __uint_as_float(c0.w << 16);
        acc[7] += v0 * __uint_as_float(c0.w & 0xFFFF0000u);
        acc[0] += v1 * __uint_as_float(c1.x << 16);
        acc[1] += v1 * __uint_as_float(c1.x & 0xFFFF0000u);
        acc[2] += v1 * __uint_as_float(c1.y << 16);
        acc[3] += v1 * __uint_as_float(c1.y & 0xFFFF0000u);
        acc[4] += v1 * __uint_as_float(c1.z << 16);
        acc[5] += v1 * __uint_as_float(c1.z & 0xFFFF0000u);
        acc[6] += v1 * __uint_as_float(c1.w << 16);
        acc[7] += v1 * __uint_as_float(c1.w & 0xFFFF0000u);
        acc[0] += v2 * __uint_as_float(c2.x << 16);
        acc[1] += v2 * __uint_as_float(c2.x & 0xFFFF0000u);
        acc[2] += v2 * __uint_as_float(c2.y << 16);
        acc[3] += v2 * __uint_as_float(c2.y & 0xFFFF0000u);
        acc[4] += v2 * __uint_as_float(c2.z << 16);
        acc[5] += v2 * __uint_as_float(c2.z & 0xFFFF0000u);
        acc[6] += v2 * __uint_as_float(c2.w << 16);
        acc[7] += v2 * __uint_as_float(c2.w & 0xFFFF0000u);
        acc[0] += v3 * __uint_as_float(c3.x << 16);
        acc[1] += v3 * __uint_as_float(c3.x & 0xFFFF0000u);
        acc[2] += v3 * __uint_as_float(c3.y << 16);
        acc[3] += v3 * __uint_as_float(c3.y & 0xFFFF0000u);
        acc[4] += v3 * __uint_as_float(c3.z << 16);
        acc[5] += v3 * __uint_as_float(c3.z & 0xFFFF0000u);
        acc[6] += v3 * __uint_as_float(c3.w << 16);
        acc[7] += v3 * __uint_as_float(c3.w & 0xFFFF0000u);
    }
    float m = mu[b], sd = stdv[b];
    float res[8];
    #pragma unroll
    for (int i = 0; i < 8; i++) res[i] = acc[i] * sd + m;
    float* op = out + (size_t)b * D_N + t * 8;
    *(float4*)(op)     = *(float4*)&res[0];
    *(float4*)(op + 4) = *(float4*)&res[4];
}

extern "C" void kernel_launch(void* const* d_in, const int* in_sizes, int n_in,
                              void* d_out, int out_size, void* d_ws, size_t ws_size,
                              hipStream_t stream) {
    const float* txt  = (const float*)d_in[0];
    const float* Wenc = (const float*)d_in[1];
    const float* Wdec = (const float*)d_in[2];
    float* recons = (float*)d_out;
    float* lat    = (float*)d_out + (size_t)B_N * D_N;

    char* p = (char*)d_ws;
    unsigned short* xnbf = (unsigned short*)p;  p += (size_t)B_N * D_N * 2;   // 4 MB
    unsigned short* Wbf  = (unsigned short*)p;  p += (size_t)H_N * D_N * 2;   // 64 MB
    unsigned short* Wdt  = (unsigned short*)p;  p += (size_t)H_N * D_N * 2;   // 64 MB
    double* invn_d = (double*)p;  p += (size_t)H_N * 8;                       // 256 KB
    double* mud    = (double*)p;  p += (size_t)B_N * 8;
    double* sivd   = (double*)p;  p += (size_t)B_N * 8;
    float* muv = (float*)p;       p += (size_t)B_N * 4;
    float* stdv = (float*)p;      p += (size_t)B_N * 4;
    int* candidx = (int*)p;       p += (size_t)B_N * CAP_C * 4;               // 3.1 MB
    float* candval = (float*)p;   p += (size_t)B_N * CAP_C * 4;               // 3.1 MB
    int* selidx = (int*)p;        p += (size_t)B_N * K_SEL * 4;
    float* selval = (float*)p;    p += (size_t)B_N * K_SEL * 4;

    ln_kernel<<<B_N, 256, 0, stream>>>(txt, xnbf, muv, stdv, mud, sivd);
    wconv_kernel<<<H_N, 256, 0, stream>>>(Wenc, Wbf, invn_d);
    enc_gemm_bf16<<<dim3(B_N / 256, H_N / 256), 512, 0, stream>>>(xnbf, Wbf, lat);
    transpose_kernel<<<dim3(H_N / 32, D_N / 64), dim3(32, 8), 0, stream>>>(Wdec, Wdt);
    candk_kernel<<<B_N, 1024, 0, stream>>>(lat, candidx, candval);
    resolve_kernel<<<B_N, 512, 0, stream>>>(txt, Wenc, invn_d, candidx, candval, selidx, selval);
    decode_kernel<<<B_N, 128, 0, stream>>>(selidx, selval, Wdt, muv, stdv, recons);
}

// Round 23
// 582.697 us; speedup vs baseline: 1.0378x; 1.0378x over previous
//
#include <hip/hip_runtime.h>
#include <math.h>

#define B_N 2048
#define D_N 1024
#define H_N 32768
#define K_SEL 256
#define M_CAND 320
#define CAP_C 384
#define BAND_CAP 160
#define DELTA 0.03f
#define EPS_V 1e-5f

typedef __bf16 bf16x8 __attribute__((ext_vector_type(8)));
typedef float f32x4 __attribute__((ext_vector_type(4)));

__device__ __forceinline__ unsigned short f2bf(float f) {
    unsigned u = __float_as_uint(f);
    unsigned r = u + 0x7FFFu + ((u >> 16) & 1u);   // RNE
    return (unsigned short)(r >> 16);
}

__device__ __forceinline__ float bf2f(unsigned short b) {
    return __uint_as_float((unsigned)b << 16);
}

// async global->LDS, 16B per lane; LDS dest is wave-uniform base + lane*16
__device__ __forceinline__ void gload16(const void* g, void* l) {
    __builtin_amdgcn_global_load_lds(
        (const __attribute__((address_space(1))) void*)g,
        (__attribute__((address_space(3))) void*)l, 16, 0, 0);
}

// ---------------- LN preprocess (f64 stats) -> bf16 xn + f32/f64 mu,std ----------------
__global__ __launch_bounds__(256) void ln_kernel(const float* __restrict__ x,
        unsigned short* __restrict__ xnbf, float* __restrict__ mu_out, float* __restrict__ std_out,
        double* __restrict__ mud, double* __restrict__ sivd) {
    int b = blockIdx.x, t = threadIdx.x;
    const float4* row = (const float4*)(x + (size_t)b * D_N);
    float4 v = row[t];
    double s  = (double)v.x + (double)v.y + (double)v.z + (double)v.w;
    double ss = (double)v.x*v.x + (double)v.y*v.y + (double)v.z*v.z + (double)v.w*v.w;
    #pragma unroll
    for (int off = 32; off > 0; off >>= 1) {
        s  += __shfl_down(s, off);
        ss += __shfl_down(ss, off);
    }
    __shared__ double ls[4], lss[4];
    __shared__ double smu, sinv;
    int w = t >> 6;
    if ((t & 63) == 0) { ls[w] = s; lss[w] = ss; }
    __syncthreads();
    if (t == 0) {
        double S  = ls[0] + ls[1] + ls[2] + ls[3];
        double SS = lss[0] + lss[1] + lss[2] + lss[3];
        double mu = S / (double)D_N;
        double var = (SS - S * S / (double)D_N) / (double)(D_N - 1);
        double sd = sqrt(var > 0.0 ? var : 0.0);
        smu = mu; sinv = 1.0 / (sd + 1e-5);
        mu_out[b] = (float)mu; std_out[b] = (float)sd;
        mud[b] = mu; sivd[b] = sinv;
    }
    __syncthreads();
    double mu = smu, inv = sinv;
    ushort4 o;
    o.x = f2bf((float)(((double)v.x - mu) * inv)); o.y = f2bf((float)(((double)v.y - mu) * inv));
    o.z = f2bf((float)(((double)v.z - mu) * inv)); o.w = f2bf((float)(((double)v.w - mu) * inv));
    *(ushort4*)(xnbf + (size_t)b * D_N + t * 4) = o;
}

// ---------------- W_enc: f64 row norm, bf16 normalized rows ----------------
__global__ __launch_bounds__(256) void wconv_kernel(const float* __restrict__ W,
        unsigned short* __restrict__ Wbf, double* __restrict__ inv_norm_d) {
    int h = blockIdx.x, t = threadIdx.x;
    const float4* row = (const float4*)(W + (size_t)h * D_N);
    float4 v = row[t];
    double ss = (double)v.x*v.x + (double)v.y*v.y + (double)v.z*v.z + (double)v.w*v.w;
    #pragma unroll
    for (int off = 32; off > 0; off >>= 1) ss += __shfl_down(ss, off);
    __shared__ double lss[4];
    __shared__ float sinv;
    int w = t >> 6;
    if ((t & 63) == 0) lss[w] = ss;
    __syncthreads();
    if (t == 0) {
        double SS = lss[0] + lss[1] + lss[2] + lss[3];
        double n = sqrt(SS);
        if (n < 1e-12) n = 1e-12;
        inv_norm_d[h] = 1.0 / n;
        sinv = (float)(1.0 / n);
    }
    __syncthreads();
    float invf = sinv;
    ushort4 o;
    o.x = f2bf(v.x * invf); o.y = f2bf(v.y * invf);
    o.z = f2bf(v.z * invf); o.w = f2bf(v.w * invf);
    *(ushort4*)(Wbf + (size_t)h * D_N + t * 4) = o;
}

// ---------------- bf16 MFMA GEMM: BK=64, double-buffered global_load_lds,
//   counted vmcnt(8) + raw barriers, pre-swizzled global source, bm-fastest grid ----------
// (r13/r16/r20 configuration verbatim — best measured; r22's 256^2 tile regressed
//  on occupancy: 1 block/CU left no waves to absorb the stage/drain phases)
__global__ __launch_bounds__(256) void enc_gemm_bf16(const unsigned short* __restrict__ A,
        const unsigned short* __restrict__ Bm, float* __restrict__ C) {
    __shared__ alignas(16) unsigned short SM[4 * 128 * 64];
    int t = threadIdx.x;
    int w = t >> 6, lane = t & 63;
    int bm = blockIdx.x, bn = blockIdx.y;    // bm fastest (B-panel locality)
    int wr = w >> 1, wc = w & 1;
    int fr = lane & 15, kq = lane >> 4;

    size_t arow0 = (size_t)bm * 128;
    size_t brow0 = (size_t)bn * 128;

    int rsub = lane >> 3;
    int jl   = (lane & 7) ^ rsub;
    const unsigned short* gAq[4];
    const unsigned short* gBq[4];
    #pragma unroll
    for (int q = 0; q < 4; q++) {
        int row = w * 32 + q * 8 + rsub;
        gAq[q] = A  + (arow0 + row) * D_N + jl * 8;
        gBq[q] = Bm + (brow0 + row) * D_N + jl * 8;
    }

    f32x4 acc[4][4];
    #pragma unroll
    for (int i = 0; i < 4; i++)
        #pragma unroll
        for (int j = 0; j < 4; j++)
            acc[i][j] = (f32x4){0.f, 0.f, 0.f, 0.f};

    auto STAGE = [&](int buf, int k0) {
        char* Ab = (char*)(SM + buf * 16384);
        char* Bb = Ab + 16384;
        #pragma unroll
        for (int q = 0; q < 4; q++)
            gload16(gAq[q] + k0, Ab + (w * 4 + q) * 1024);
        #pragma unroll
        for (int q = 0; q < 4; q++)
            gload16(gBq[q] + k0, Bb + (w * 4 + q) * 1024);
    };

    STAGE(0, 0);

    for (int ks = 0; ks < D_N / 64; ks++) {
        int cur = ks & 1;
        if (ks + 1 < D_N / 64) {
            STAGE(cur ^ 1, (ks + 1) * 64);
            asm volatile("s_waitcnt vmcnt(8)" ::: "memory");
        } else {
            asm volatile("s_waitcnt vmcnt(0)" ::: "memory");
        }
        __builtin_amdgcn_s_barrier();
        __builtin_amdgcn_sched_barrier(0);

        const unsigned short* Ab = SM + cur * 16384;
        const unsigned short* Bb = Ab + 8192;
        #pragma unroll
        for (int kk = 0; kk < 2; kk++) {
            bf16x8 af[4], bfr[4];
            #pragma unroll
            for (int i = 0; i < 4; i++) {
                int ra = wr * 64 + i * 16 + fr;
                int ja = (kk * 4 + kq) ^ (ra & 7);
                af[i] = *(const bf16x8*)&Ab[ra * 64 + ja * 8];
                int rb = wc * 64 + i * 16 + fr;
                int jb = (kk * 4 + kq) ^ (rb & 7);
                bfr[i] = *(const bf16x8*)&Bb[rb * 64 + jb * 8];
            }
            #pragma unroll
            for (int i = 0; i < 4; i++)
                #pragma unroll
                for (int j = 0; j < 4; j++)
                    acc[i][j] = __builtin_amdgcn_mfma_f32_16x16x32_bf16(af[i], bfr[j], acc[i][j], 0, 0, 0);
        }

        asm volatile("s_waitcnt lgkmcnt(0)" ::: "memory");
        __builtin_amdgcn_sched_barrier(0);
        __builtin_amdgcn_s_barrier();
        __builtin_amdgcn_sched_barrier(0);
    }

    #pragma unroll
    for (int i = 0; i < 4; i++) {
        int r0 = bm * 128 + wr * 64 + i * 16 + kq * 4;
        #pragma unroll
        for (int j = 0; j < 4; j++) {
            int c = bn * 128 + wc * 64 + j * 16 + fr;
            #pragma unroll
            for (int r = 0; r < 4; r++)
                __builtin_nontemporal_store(acc[i][j][r], &C[(size_t)(r0 + r) * H_N + c]);
        }
    }
}

// ---------------- W_dec transpose [D][H] -> bf16 [H][D], ushort2 writes ----------------
__global__ void transpose_kernel(const float* __restrict__ in, unsigned short* __restrict__ out) {
    __shared__ float tile[64][33];   // [d][h]
    int tx = threadIdx.x, ty = threadIdx.y;
    int x  = blockIdx.x * 32 + tx;        // h
    int y0 = blockIdx.y * 64;             // d base
    #pragma unroll
    for (int j = ty; j < 64; j += 8)
        tile[j][tx] = in[(size_t)(y0 + j) * H_N + x];
    __syncthreads();
    int d2 = tx * 2;
    int hbase = blockIdx.x * 32;
    #pragma unroll
    for (int j = ty; j < 32; j += 8) {
        ushort2 o;
        o.x = f2bf(tile[d2][j]);
        o.y = f2bf(tile[d2 + 1][j]);
        *(ushort2*)(out + (size_t)(hbase + j) * D_N + y0 + d2) = o;
    }
}

// ---------------- candidate extraction: thresholded histogram, wave-parallel scan ----------
__global__ __launch_bounds__(1024) void candk_kernel(const float* __restrict__ lat,
        int* __restrict__ cand_idx, float* __restrict__ cand_val) {
    int b = blockIdx.x, t = threadIdx.x;
    const float4* row4 = (const float4*)(lat + (size_t)b * H_N);
    __shared__ unsigned hist[256];
    __shared__ int sh_tb, sh_pos;

    float4 fv[8];
    #pragma unroll
    for (int j = 0; j < 8; j++)
        fv[j] = row4[t + (j << 10)];

    if (t < 256) hist[t] = 0;
    if (t == 0) { sh_pos = 0; sh_tb = 0; }
    __syncthreads();
    #pragma unroll
    for (int j = 0; j < 8; j++) {
        const float4 v = fv[j];
        #pragma unroll
        for (int c = 0; c < 4; c++) {
            float f = (c == 0) ? v.x : (c == 1) ? v.y : (c == 2) ? v.z : v.w;
            if (f >= 1.75f) {
                int bin = (int)((f - 1.75f) * 128.0f);
                bin = bin > 255 ? 255 : bin;
                atomicAdd(&hist[bin], 1u);
            }
        }
    }
    __syncthreads();
    if (t < 64) {
        unsigned h0 = hist[4 * t], h1 = hist[4 * t + 1];
        unsigned h2 = hist[4 * t + 2], h3 = hist[4 * t + 3];
        unsigned s = h0 + h1 + h2 + h3;
        #pragma unroll
        for (int off = 1; off < 64; off <<= 1) {
            unsigned v = __shfl_down(s, off);
            if (t + off < 64) s += v;
        }
        unsigned S0 = s, S1 = s - h0, S2 = S1 - h1, S3 = S2 - h2;
        int mj = -1;
        if (S0 >= (unsigned)M_CAND) mj = 4 * t;
        if (S1 >= (unsigned)M_CAND) mj = 4 * t + 1;
        if (S2 >= (unsigned)M_CAND) mj = 4 * t + 2;
        if (S3 >= (unsigned)M_CAND) mj = 4 * t + 3;
        #pragma unroll
        for (int off = 32; off > 0; off >>= 1) {
            int v = __shfl_down(mj, off);
            if (t + off < 64 && v > mj) mj = v;
        }
        if (t == 0) sh_tb = mj > 0 ? mj : 0;
    }
    __syncthreads();
    int tb = sh_tb;
    #pragma unroll
    for (int j = 0; j < 8; j++) {
        const float4 v = fv[j];
        #pragma unroll
        for (int c = 0; c < 4; c++) {
            float f = (c == 0) ? v.x : (c == 1) ? v.y : (c == 2) ? v.z : v.w;
            if (f >= 1.75f) {
                int bin = (int)((f - 1.75f) * 128.0f);
                bin = bin > 255 ? 255 : bin;
                if (bin >= tb) {
                    int p = atomicAdd(&sh_pos, 1);
                    if (p < CAP_C) {
                        cand_idx[(size_t)b * CAP_C + p] = 4 * (t + (j << 10)) + c;
                        cand_val[(size_t)b * CAP_C + p] = f;
                    }
                }
            }
        }
    }
    __syncthreads();
    int pos = sh_pos < CAP_C ? sh_pos : CAP_C;
    for (int p = pos + t; p < CAP_C; p += 1024) {
        cand_idx[(size_t)b * CAP_C + p] = -(p + 1);
        cand_val[(size_t)b * CAP_C + p] = -1e30f;
    }
}

// ---------------- fused band-classify + f64 boundary refine + select ----------------
__global__ __launch_bounds__(512) void resolve_kernel(const float* __restrict__ x,
        const float* __restrict__ Wenc, const double* __restrict__ invn_d,
        const int* __restrict__ candidx, const float* __restrict__ candval,
        int* __restrict__ sel_idx, float* __restrict__ sel_val) {
    int b = blockIdx.x, t = threadIdx.x;
    int lane = t & 63, w = t >> 6;
    __shared__ float cv[CAP_C];
    __shared__ int   ci[CAP_C];
    __shared__ float sh_v256;
    __shared__ int sh_nIn, sh_bcnt;
    __shared__ int bmem[BAND_CAP];
    __shared__ double bval[BAND_CAP];
    __shared__ double xs[D_N];
    __shared__ double red[8];
    __shared__ double smu, sinv;

    if (t == 0) { sh_nIn = 0; sh_bcnt = 0; }
    if (t < CAP_C) {
        cv[t] = candval[(size_t)b * CAP_C + t];
        ci[t] = candidx[(size_t)b * CAP_C + t];
    }
    float4 v;
    if (t < 256) {
        v = ((const float4*)(x + (size_t)b * D_N))[t];
        double s  = (double)v.x + (double)v.y + (double)v.z + (double)v.w;
        double ss = (double)v.x*v.x + (double)v.y*v.y + (double)v.z*v.z + (double)v.w*v.w;
        #pragma unroll
        for (int off = 32; off > 0; off >>= 1) {
            s  += __shfl_down(s, off);
            ss += __shfl_down(ss, off);
        }
        if (lane == 0) { red[w] = s; red[4 + w] = ss; }
    }
    __syncthreads();
    if (t == 0) {
        double S  = red[0] + red[1] + red[2] + red[3];
        double SS = red[4] + red[5] + red[6] + red[7];
        double mu = S / (double)D_N;
        double var = (SS - S * S / (double)D_N) / (double)(D_N - 1);
        double sd = sqrt(var > 0.0 ? var : 0.0);
        smu = mu; sinv = 1.0 / (sd + 1e-5);
    }
    __syncthreads();
    if (t < 256) {
        double mu = smu, inv = sinv;
        xs[4*t + 0] = ((double)v.x - mu) * inv;
        xs[4*t + 1] = ((double)v.y - mu) * inv;
        xs[4*t + 2] = ((double)v.z - mu) * inv;
        xs[4*t + 3] = ((double)v.w - mu) * inv;
    }
    int myr = 0;
    if (t < CAP_C) {
        float vv = cv[t]; int id = ci[t];
        for (int j = 0; j < CAP_C; j++) {
            float vj = cv[j];
            myr += (vj > vv) || (vj == vv && ci[j] < id);
        }
        if (myr == 255) sh_v256 = cv[t];
    }
    __syncthreads();
    float v256 = sh_v256;
    if (t < CAP_C) {
        float vv = cv[t];
        if (vv > v256 + DELTA) {
            sel_idx[(size_t)b * K_SEL + myr] = ci[t];
            sel_val[(size_t)b * K_SEL + myr] = vv;
            atomicAdd(&sh_nIn, 1);
        } else if (vv >= v256 - DELTA) {
            int p = atomicAdd(&sh_bcnt, 1);
            if (p < BAND_CAP) bmem[p] = t;
        }
    }
    __syncthreads();

    double xr[16];
    #pragma unroll
    for (int r = 0; r < 4; r++)
        #pragma unroll
        for (int j = 0; j < 4; j++)
            xr[r * 4 + j] = xs[256 * r + 4 * lane + j];

    int bcnt = sh_bcnt < BAND_CAP ? sh_bcnt : BAND_CAP;
    const float4* W4 = (const float4*)Wenc;
    for (int m = w; m < bcnt; m += 8) {
        int c = bmem[m];
        int h = ci[c];
        const float4* wr = W4 + (size_t)h * 256 + lane;
        float4 w0 = wr[0], w1 = wr[64], w2 = wr[128], w3 = wr[192];
        double a0 = (double)w0.x*xr[0]  + (double)w0.y*xr[1]  + (double)w0.z*xr[2]  + (double)w0.w*xr[3];
        double a1 = (double)w1.x*xr[4]  + (double)w1.y*xr[5]  + (double)w1.z*xr[6]  + (double)w1.w*xr[7];
        double a2 = (double)w2.x*xr[8]  + (double)w2.y*xr[9]  + (double)w2.z*xr[10] + (double)w2.w*xr[11];
        double a3 = (double)w3.x*xr[12] + (double)w3.y*xr[13] + (double)w3.z*xr[14] + (double)w3.w*xr[15];
        double p = (a0 + a1) + (a2 + a3);
        #pragma unroll
        for (int off = 32; off > 0; off >>= 1) p += __shfl_down(p, off);
        if (lane == 0) bval[m] = p * invn_d[h];
    }
    __syncthreads();

    int nIn = sh_nIn;
    int take = K_SEL - nIn;
    if (t < bcnt) {
        double vv = bval[t]; int id = ci[bmem[t]];
        int rb = 0;
        for (int j = 0; j < bcnt; j++) {
            double vj = bval[j];
            rb += (vj > vv) || (vj == vv && ci[bmem[j]] < id);
        }
        if (rb < take) {
            sel_idx[(size_t)b * K_SEL + nIn + rb] = id;
            sel_val[(size_t)b * K_SEL + nIn + rb] = (float)vv;
        }
    }
}

// ---------------- sparse decode (bf16 Wdt) + denorm: 4-deep pipelined gather ----------------
// (r11-r18/r20 configuration verbatim — at its L3-gather floor per r21 A/B)
__global__ __launch_bounds__(256) void decode_kernel(const int* __restrict__ sel_idx,
        const float* __restrict__ sel_val, const unsigned short* __restrict__ Wdt,
        const float* __restrict__ mu, const float* __restrict__ stdv,
        float* __restrict__ out) {
    int b = blockIdx.x, t = threadIdx.x;
    __shared__ int sidx[K_SEL];
    __shared__ float sval[K_SEL];
    sidx[t] = sel_idx[(size_t)b * K_SEL + t];
    sval[t] = sel_val[(size_t)b * K_SEL + t];
    __syncthreads();
    float4 acc = {0.f, 0.f, 0.f, 0.f};
    ushort4 wb[4];
    #pragma unroll
    for (int q = 0; q < 4; q++)
        wb[q] = *(const ushort4*)(Wdt + (size_t)sidx[q] * D_N + t * 4);
    for (int k = 0; k < K_SEL; k += 4) {
        ushort4 cur0 = wb[0], cur1 = wb[1], cur2 = wb[2], cur3 = wb[3];
        if (k + 4 < K_SEL) {
            #pragma unroll
            for (int q = 0; q < 4; q++)
                wb[q] = *(const ushort4*)(Wdt + (size_t)sidx[k + 4 + q] * D_N + t * 4);
        }
        float v0 = sval[k], v1 = sval[k + 1], v2 = sval[k + 2], v3 = sval[k + 3];
        acc.x += v0 * bf2f(cur0.x); acc.y += v0 * bf2f(cur0.y);
        acc.z += v0 * bf2f(cur0.z); acc.w += v0 * bf2f(cur0.w);
        acc.x += v1 * bf2f(cur1.x); acc.y += v1 * bf2f(cur1.y);
        acc.z += v1 * bf2f(cur1.z); acc.w += v1 * bf2f(cur1.w);
        acc.x += v2 * bf2f(cur2.x); acc.y += v2 * bf2f(cur2.y);
        acc.z += v2 * bf2f(cur2.z); acc.w += v2 * bf2f(cur2.w);
        acc.x += v3 * bf2f(cur3.x); acc.y += v3 * bf2f(cur3.y);
        acc.z += v3 * bf2f(cur3.z); acc.w += v3 * bf2f(cur3.w);
    }
    float m = mu[b], sd = stdv[b];
    float4 o;
    o.x = acc.x * sd + m; o.y = acc.y * sd + m;
    o.z = acc.z * sd + m; o.w = acc.w * sd + m;
    ((float4*)(out + (size_t)b * D_N))[t] = o;
}

extern "C" void kernel_launch(void* const* d_in, const int* in_sizes, int n_in,
                              void* d_out, int out_size, void* d_ws, size_t ws_size,
                              hipStream_t stream) {
    const float* txt  = (const float*)d_in[0];
    const float* Wenc = (const float*)d_in[1];
    const float* Wdec = (const float*)d_in[2];
    float* recons = (float*)d_out;
    float* lat    = (float*)d_out + (size_t)B_N * D_N;

    char* p = (char*)d_ws;
    unsigned short* xnbf = (unsigned short*)p;  p += (size_t)B_N * D_N * 2;   // 4 MB
    unsigned short* Wbf  = (unsigned short*)p;  p += (size_t)H_N * D_N * 2;   // 64 MB
    unsigned short* Wdt  = (unsigned short*)p;  p += (size_t)H_N * D_N * 2;   // 64 MB
    double* invn_d = (double*)p;  p += (size_t)H_N * 8;                       // 256 KB
    double* mud    = (double*)p;  p += (size_t)B_N * 8;
    double* sivd   = (double*)p;  p += (size_t)B_N * 8;
    float* muv = (float*)p;       p += (size_t)B_N * 4;
    float* stdv = (float*)p;      p += (size_t)B_N * 4;
    int* candidx = (int*)p;       p += (size_t)B_N * CAP_C * 4;               // 3.1 MB
    float* candval = (float*)p;   p += (size_t)B_N * CAP_C * 4;               // 3.1 MB
    int* selidx = (int*)p;        p += (size_t)B_N * K_SEL * 4;
    float* selval = (float*)p;    p += (size_t)B_N * K_SEL * 4;

    ln_kernel<<<B_N, 256, 0, stream>>>(txt, xnbf, muv, stdv, mud, sivd);
    wconv_kernel<<<H_N, 256, 0, stream>>>(Wenc, Wbf, invn_d);
    enc_gemm_bf16<<<dim3(B_N / 128, H_N / 128), 256, 0, stream>>>(xnbf, Wbf, lat);
    transpose_kernel<<<dim3(H_N / 32, D_N / 64), dim3(32, 8), 0, stream>>>(Wdec, Wdt);
    candk_kernel<<<B_N, 1024, 0, stream>>>(lat, candidx, candval);
    resolve_kernel<<<B_N, 512, 0, stream>>>(txt, Wenc, invn_d, candidx, candval, selidx, selval);
    decode_kernel<<<B_N, 256, 0, stream>>>(selidx, selval, Wdt, muv, stdv, recons);
}